// Round 6
// baseline (229.928 us; speedup 1.0000x reference)
//
#include <hip/hip_runtime.h>
#include <math.h>

typedef unsigned short u16;
typedef unsigned int u32;
typedef __fp16 fp16x2 __attribute__((ext_vector_type(2)));
typedef _Float16 half8 __attribute__((ext_vector_type(8)));
typedef float f32x4 __attribute__((ext_vector_type(4)));

#define NH   12
#define SEQ  2048
#define CDIM 768

__device__ __forceinline__ u16 f2h(float f) {
  _Float16 h = (_Float16)f;
  return __builtin_bit_cast(u16, h);
}
__device__ __forceinline__ u32 pk2(float a, float b) {
  fp16x2 h = __builtin_amdgcn_cvt_pkrtz(a, b);    // v_cvt_pk_rtz_f16_f32
  return __builtin_bit_cast(u32, h);
}
// async global->LDS DMA, 16B per lane; LDS dest = wave-uniform base + lane*16
__device__ __forceinline__ void dma16(const u16* g, u16* l) {
  __builtin_amdgcn_global_load_lds(
      (const __attribute__((address_space(1))) u32*)g,
      (__attribute__((address_space(3))) u32*)l, 16, 0, 0);
}
// top-of-iteration publish point: own DMAs/ds_writes landed -> barrier.
// (T4: the freshly-issued batch is NOT drained here -- it gets a full
// barrier-to-barrier interval of cover, unlike __syncthreads at loop end.)
__device__ __forceinline__ void publish_vm() {
  asm volatile("s_waitcnt vmcnt(0)" ::: "memory");
  __builtin_amdgcn_s_barrier();
  __builtin_amdgcn_sched_barrier(0);
}
__device__ __forceinline__ void publish_vm_lgkm() {
  asm volatile("s_waitcnt vmcnt(0) lgkmcnt(0)" ::: "memory");
  __builtin_amdgcn_s_barrier();
  __builtin_amdgcn_sched_barrier(0);
}

// ---------------- weight converts (small, L2-resident) ----------------
// 576 blocks Wq (scaled), 1152 Wkv, 576 Wproj
__global__ __launch_bounds__(256) void cvt_w(const float* __restrict__ Wq,
                                             const float* __restrict__ Wkv,
                                             const float* __restrict__ Wp,
                                             const float* __restrict__ taup,
                                             u16* __restrict__ wqh, u16* __restrict__ wkh,
                                             u16* __restrict__ wph) {
  const long E1 = 768l * 768, E2 = E1 + 1536l * 768;
  long i = ((long)blockIdx.x * 256 + threadIdx.x) * 4;
  const float* in; u16* out; long j; float s;
  if (i < E1) {
    float t = *taup;
    float sp = (t > 20.f) ? t : log1pf(expf(t));
    s = (0.125f / (sp + 1e-6f)) * 1.44269504088896340736f;  // qkscale * log2(e)
    in = Wq; out = wqh; j = i;
  } else if (i < E2) {
    s = 1.f; in = Wkv; out = wkh; j = i - E1;
  } else {
    s = 1.f; in = Wp; out = wph; j = i - E2;
  }
  float4 f = *(const float4*)(in + j);
  *(uint2*)(out + j) = make_uint2(pk2(f.x * s, f.y * s), pk2(f.z * s, f.w * s));
}

// ---------------- NT GEMM: C[M,N] = A[M,K] @ B[N,K]^T, f16 MFMA, fp32 acc ---
// Tile 128(M) x BN(N), BK=64, K=768 (12 iters). 4 waves as 2x2 quadrants.
// NEW sync: raw s_barrier with the vmcnt/lgkm wait at the TOP of each iter
// (publish point) -- the batch issued in iter t is waited at top of t+1,
// giving it a full iteration of latency cover (old __syncthreads drained it
// at the end of the same iteration: only ~compute-duration of cover).
// MODE 0: A fp32 (x/y), fused convert via 2-deep register pipeline:
//   iter t: publish tile t+1 (ds_write from regs loaded in iter t-1),
//   issue fp32 loads for tile t+2. B (f16 weights) via global_load_lds.
// MODE 2: A=ao f16 via global_load_lds; out fp32 = acc + bias[n].
template<int MODE, int BN, int WPB>
__global__ __launch_bounds__(256, WPB) void gemm_k(
    const void* __restrict__ A0v, const void* __restrict__ A1v,
    const u16* __restrict__ B0, const u16* __restrict__ B1,
    u16* __restrict__ oq, u16* __restrict__ ok, u16* __restrict__ ovt,
    float* __restrict__ outf, const float* __restrict__ bias)
{
  constexpr int NT = BN / 32;                     // n-tiles per wave
  __shared__ __align__(16) u16 As[2][128 * 64];   // [buf][m][k] swizzled, 32 KB
  __shared__ __align__(16) u16 Bs[2][BN * 64];    // [buf][n][k] swizzled
  const int tid = threadIdx.x;
  const int wave = tid >> 6, lane = tid & 63;
  const int quad = lane >> 4, l16 = lane & 15;
  const int wr = wave >> 1, wc = wave & 1;        // wave quadrant (64m x BN/2)
  const int row0 = blockIdx.x * 128;
  const int by = blockIdx.y;

  const float* Af;            // MODE 0: fp32 A
  const u16* Ah;              // MODE 2: f16 A
  const u16* Bm; int cb;
  if (MODE == 0) {
    if (by < 6) { Af = (const float*)A0v; Bm = B0; cb = by; }
    else        { Af = (const float*)A1v; Bm = B1; cb = by - 6; }
    Ah = nullptr;
  } else {
    Ah = (const u16*)A0v; Bm = B0; cb = by; Af = nullptr;
  }
  const int col0 = cb * BN;

  const int sub = lane >> 3;                   // row within an 8-row DMA slab
  const int csw = ((lane & 7) ^ sub) * 8;      // swizzled source chunk (elems)

  f32x4 acc[4][NT] = {};
  f32x4 areg[4][2];                            // MODE 0: staged fp32 A (32 VGPR)

  auto loadA = [&](int k0) {                   // MODE 0: issue global f32 loads
    #pragma unroll
    for (int i = 0; i < 4; i++) {
      int ii = wave * 4 + i;
      const float* p = Af + (size_t)(row0 + ii * 8 + sub) * 768 + k0 + csw;
      areg[i][0] = *(const f32x4*)p;
      areg[i][1] = *(const f32x4*)(p + 4);
    }
  };
  auto writeA = [&](int bsel) {                // MODE 0: cvt + LDS write
    #pragma unroll
    for (int i = 0; i < 4; i++) {
      int ii = wave * 4 + i;
      uint4 w = make_uint4(pk2(areg[i][0][0], areg[i][0][1]), pk2(areg[i][0][2], areg[i][0][3]),
                           pk2(areg[i][1][0], areg[i][1][1]), pk2(areg[i][1][2], areg[i][1][3]));
      *(uint4*)&As[bsel][ii * 512 + lane * 8] = w;
    }
  };
  auto stageA_dma = [&](int k0, int bsel) {    // MODE 2: f16 DMA
    #pragma unroll
    for (int i = 0; i < 4; i++) {
      int ii = wave * 4 + i;
      dma16(Ah + (size_t)(row0 + ii * 8 + sub) * 768 + k0 + csw, &As[bsel][ii * 512]);
    }
  };
  auto stageB = [&](int k0, int bsel) {
    #pragma unroll
    for (int i = 0; i < BN / 32; i++) {
      int ii = wave * (BN / 32) + i;           // B slabs 0..BN/8-1
      dma16(Bm + (size_t)(col0 + ii * 8 + sub) * 768 + k0 + csw, &Bs[bsel][ii * 512]);
    }
  };
  auto compute = [&](int bsel) {
    const u16* Asp = As[bsel];
    const u16* Bsp = Bs[bsel];
    #pragma unroll
    for (int ks = 0; ks < 2; ks++) {
      half8 af[4], bfr[NT];
      #pragma unroll
      for (int mt = 0; mt < 4; mt++)
        af[mt] = *(const half8*)&Asp[(wr * 64 + mt * 16 + l16) * 64 + (((ks * 4 + quad) ^ (l16 & 7)) * 8)];
      #pragma unroll
      for (int nt = 0; nt < NT; nt++)
        bfr[nt] = *(const half8*)&Bsp[(wc * (BN / 2) + nt * 16 + l16) * 64 + (((ks * 4 + quad) ^ (l16 & 7)) * 8)];
      #pragma unroll
      for (int mt = 0; mt < 4; mt++)
        #pragma unroll
        for (int nt = 0; nt < NT; nt++)
          acc[mt][nt] = __builtin_amdgcn_mfma_f32_16x16x32_f16(af[mt], bfr[nt], acc[mt][nt], 0, 0, 0);
    }
  };

  // prologue
  if (MODE == 0) {
    stageB(0, 0);
    loadA(0);
    writeA(0);          // compiler waits the A-loads; tile0 -> As[0]
    loadA(64);          // tile1 -> regs
  } else {
    stageA_dma(0, 0);
    stageB(0, 0);
  }

  #pragma unroll 1
  for (int t = 0; t < 12; t++) {
    const int cur = t & 1;
    if (MODE == 0) publish_vm_lgkm();          // batch(t) landed everywhere
    else           publish_vm();
    if (t + 1 < 12) {
      if (MODE == 0) writeA(cur ^ 1);          // publish tile t+1 (regs landed)
      else stageA_dma((t + 1) << 6, cur ^ 1);
      stageB((t + 1) << 6, cur ^ 1);
    }
    if (MODE == 0 && t + 2 < 12) loadA((t + 2) << 6);   // 2-deep A prefetch
    compute(cur);
  }

  // epilogue: C layout col=lane&15, row=quad*4+reg
  #pragma unroll
  for (int mt = 0; mt < 4; mt++)
  #pragma unroll
  for (int nt = 0; nt < NT; nt++) {
    int gm0 = row0 + wr * 64 + mt * 16 + quad * 4;
    int gn = col0 + wc * (BN / 2) + nt * 16 + l16;
    f32x4 v = acc[mt][nt];
    if (MODE == 0) {
      int b = gm0 >> 11, n0 = gm0 & 2047;
      if (by < 6) {
        int h = gn >> 6, d = gn & 63;
        size_t base = (((size_t)(b * NH + h)) * SEQ + n0) * 64 + d;
        #pragma unroll
        for (int r = 0; r < 4; r++) oq[base + (size_t)r * 64] = f2h(v[r]);
      } else if (gn < CDIM) {
        int h = gn >> 6, d = gn & 63;
        size_t base = (((size_t)(b * NH + h)) * SEQ + n0) * 64 + d;
        #pragma unroll
        for (int r = 0; r < 4; r++) ok[base + (size_t)r * 64] = f2h(v[r]);
      } else {
        int c = gn - CDIM;
        int h = c >> 6, d = c & 63;
        *(uint2*)&ovt[(((size_t)(b * NH + h)) * 64 + d) * SEQ + n0] =
            make_uint2(pk2(v[0], v[1]), pk2(v[2], v[3]));   // V^T: 4 consecutive n
      }
    } else {
      float bv = bias[gn];
      #pragma unroll
      for (int r = 0; r < 4; r++)
        outf[(size_t)(gm0 + r) * CDIM + gn] = v[r] + bv;
    }
  }
}

// ---------------- flash attention (transposed-S, f16, no-max softmax) ------
// QBLK=128, grid 768, chunked XCD swizzle (96 blocks = 6 heads/XCD -> 3 MB L2).
// Round-4 compute body (T15 pipeline reverted: NULL). NEW sync: publish_vm at
// TOP of each iter -- the K/V batch issued in iter t is waited at top of t+1
// (full-iteration cover), not drained at the end of iter t like __syncthreads.
// Ps is per-wave (no cross-wave LDS publish -> no lgkm in the barrier).
__global__ __launch_bounds__(256, 3) void attn_kernel(
    const u16* __restrict__ Q, const u16* __restrict__ Kb,
    const u16* __restrict__ Vtg, u16* __restrict__ Ob)
{
  __shared__ __align__(16) u16 Ks[2][64 * 64];    // [buf][kk][d] swizzled, 2x8 KB
  __shared__ __align__(16) u16 Vs[2][64 * 64];    // [buf][d][kk] swizzled, 2x8 KB
  __shared__ __align__(16) u16 Ps[4 * 16 * 64];   // per-wave 16x64 swizzled, 8 KB

  // bijective chunked XCD swizzle: 768 blocks = 8 XCDs x 96
  const int bid = (blockIdx.x & 7) * 96 + (blockIdx.x >> 3);
  const int qt = bid & 15;
  const int bh = bid >> 4;
  const int b = bh / NH, h = bh % NH;
  const u16* Qp = Q   + (size_t)bh * SEQ * 64;
  const u16* Kp = Kb  + (size_t)bh * SEQ * 64;
  const u16* Vp = Vtg + (size_t)bh * 64 * SEQ;

  const int tid = threadIdx.x;
  const int wave = tid >> 6, lane = tid & 63;
  const int quad = lane >> 4, l16 = lane & 15;
  const int sub = lane >> 3;
  const int csw = ((lane & 7) ^ sub) * 8;
  u16* Pw = Ps + wave * 16 * 64;

  half8 vone;
  #pragma unroll
  for (int j = 0; j < 8; j++) vone[j] = (_Float16)1.0f;

  // Q fragments (B-operand): Q[m=l16][d=ks*32+quad*8+j], scale pre-folded
  half8 qf[2][2];
  #pragma unroll
  for (int mt = 0; mt < 2; mt++)
    #pragma unroll
    for (int ks = 0; ks < 2; ks++)
      qf[mt][ks] = *(const half8*)(Qp + (size_t)(qt * 128 + wave * 32 + mt * 16 + l16) * 64 + ks * 32 + quad * 8);

  f32x4 oacc[2][4] = {};
  f32x4 lacc[2] = {};                          // row-sums via MFMA w/ ones

  auto stage = [&](int kt, int bsel) {
    #pragma unroll
    for (int i = 0; i < 2; i++) {
      int ii = wave * 2 + i;                   // slabs 0..7 (8 rows each)
      dma16(Kp + (size_t)(kt * 64 + ii * 8 + sub) * 64 + csw, &Ks[bsel][ii * 512]);
      dma16(Vp + (size_t)(ii * 8 + sub) * SEQ + kt * 64 + csw, &Vs[bsel][ii * 512]);
    }
  };

  stage(0, 0);

  #pragma unroll 1
  for (int kt = 0; kt < SEQ / 64; kt++) {
    const int cur = kt & 1;
    publish_vm();                              // batch(kt) landed everywhere
    if (kt + 1 < SEQ / 64) stage(kt + 1, cur ^ 1);   // full-iter cover
    const u16* Ksp = Ks[cur];
    const u16* Vsp = Vs[cur];

    // St = K Q^T : sacc[mt][ntk] holds St[kk=ntk*16+quad*4+r][m=l16]
    f32x4 sacc[2][4] = {};
    __builtin_amdgcn_s_setprio(1);
    #pragma unroll
    for (int ks = 0; ks < 2; ks++) {
      #pragma unroll
      for (int ntk = 0; ntk < 4; ntk++) {
        half8 kf = *(const half8*)&Ksp[(ntk * 16 + l16) * 64 + (((ks * 4 + quad) ^ (l16 & 7)) * 8)];
        #pragma unroll
        for (int mt = 0; mt < 2; mt++)
          sacc[mt][ntk] = __builtin_amdgcn_mfma_f32_16x16x32_f16(kf, qf[mt][ks], sacc[mt][ntk], 0, 0, 0);
      }
    }
    __builtin_amdgcn_s_setprio(0);

    // softmax (fixed shift): p = exp2(s); P -> swizzled Ps (C->A layout), per mt
    half8 pf[2][2];
    #pragma unroll
    for (int mt = 0; mt < 2; mt++) {
      #pragma unroll
      for (int ntk = 0; ntk < 4; ntk++) {
        float p0 = __builtin_amdgcn_exp2f(sacc[mt][ntk][0]);
        float p1 = __builtin_amdgcn_exp2f(sacc[mt][ntk][1]);
        float p2 = __builtin_amdgcn_exp2f(sacc[mt][ntk][2]);
        float p3 = __builtin_amdgcn_exp2f(sacc[mt][ntk][3]);
        *(uint2*)&Pw[l16 * 64 + (((ntk * 2 + (quad >> 1)) ^ (l16 & 7)) * 8) + (quad & 1) * 4] =
            make_uint2(pk2(p0, p1), pk2(p2, p3));
      }
      pf[mt][0] = *(const half8*)&Pw[l16 * 64 + ((quad ^ (l16 & 7)) * 8)];
      pf[mt][1] = *(const half8*)&Pw[l16 * 64 + (((4 + quad) ^ (l16 & 7)) * 8)];
    }

    // O += P V (vf reused across mt); l += P 1 on the matrix pipe
    __builtin_amdgcn_s_setprio(1);
    #pragma unroll
    for (int ks = 0; ks < 2; ks++) {
      #pragma unroll
      for (int dt = 0; dt < 4; dt++) {
        half8 vf = *(const half8*)&Vsp[(dt * 16 + l16) * 64 + (((ks * 4 + quad) ^ (l16 & 7)) * 8)];
        #pragma unroll
        for (int mt = 0; mt < 2; mt++)
          oacc[mt][dt] = __builtin_amdgcn_mfma_f32_16x16x32_f16(pf[mt][ks], vf, oacc[mt][dt], 0, 0, 0);
      }
      #pragma unroll
      for (int mt = 0; mt < 2; mt++)
        lacc[mt] = __builtin_amdgcn_mfma_f32_16x16x32_f16(pf[mt][ks], vone, lacc[mt], 0, 0, 0);
    }
    __builtin_amdgcn_s_setprio(0);
  }

  // epilogue: O / l -> ao[b][n][h*64+d] (f16); lacc row layout == oacc rows
  #pragma unroll
  for (int mt = 0; mt < 2; mt++) {
    #pragma unroll
    for (int r = 0; r < 4; r++) {
      float inv = 1.0f / lacc[mt][r];
      int n = qt * 128 + wave * 32 + mt * 16 + quad * 4 + r;
      size_t base = ((size_t)b * SEQ + n) * CDIM + h * 64;
      #pragma unroll
      for (int dt = 0; dt < 4; dt++)
        Ob[base + dt * 16 + l16] = f2h(oacc[mt][dt][r] * inv);
    }
  }
}

// ---------------- launch ----------------
extern "C" void kernel_launch(void* const* d_in, const int* in_sizes, int n_in,
                              void* d_out, int out_size, void* d_ws, size_t ws_size,
                              hipStream_t stream)
{
  const float* x     = (const float*)d_in[0];
  const float* y     = (const float*)d_in[1];
  const float* Wq    = (const float*)d_in[2];
  const float* Wkv   = (const float*)d_in[3];
  const float* taup  = (const float*)d_in[4];
  const float* Wproj = (const float*)d_in[5];
  const float* bproj = (const float*)d_in[6];
  float* out = (float*)d_out;

  char* ws = (char*)d_ws;
  size_t off = 0;
  auto alloc = [&](size_t bytes) { char* p = ws + off; off += bytes; return p; };
  u16* wqh = (u16*)alloc(768ull * 768 * 2);
  u16* wkh = (u16*)alloc(1536ull * 768 * 2);
  u16* wph = (u16*)alloc(768ull * 768 * 2);
  u16* qb  = (u16*)alloc(8192ull * 768 * 2);   // [B,H,N,D] f16, scale folded
  u16* kb  = (u16*)alloc(8192ull * 768 * 2);   // [B,H,N,D]
  u16* vtb = (u16*)alloc(8192ull * 768 * 2);   // [B,H,D,N]
  u16* ao  = (u16*)alloc(8192ull * 768 * 2);   // [B,N,C]

  cvt_w<<<2304, 256, 0, stream>>>(Wq, Wkv, Wproj, taup, wqh, wkh, wph);

  // fused QKV GEMM, fp32 A with in-kernel convert: by<6 -> Q, by in [6,18) -> KV
  gemm_k<0, 128, 2><<<dim3(64, 18), 256, 0, stream>>>(x, y, wqh, wkh, qb, kb, vtb, nullptr, nullptr);
  attn_kernel<<<dim3(768), 256, 0, stream>>>(qb, kb, vtb, ao);
  gemm_k<2, 64, 3><<<dim3(64, 12), 256, 0, stream>>>(ao, nullptr, wph, nullptr, nullptr, nullptr, nullptr, out, bproj);
}

// Round 8
// 223.713 us; speedup vs baseline: 1.0278x; 1.0278x over previous
//
#include <hip/hip_runtime.h>
#include <math.h>

typedef unsigned short u16;
typedef unsigned int u32;
typedef __fp16 fp16x2 __attribute__((ext_vector_type(2)));
typedef _Float16 half8 __attribute__((ext_vector_type(8)));
typedef float f32x4 __attribute__((ext_vector_type(4)));

#define NH   12
#define SEQ  2048
#define CDIM 768

__device__ __forceinline__ u16 f2h(float f) {
  _Float16 h = (_Float16)f;
  return __builtin_bit_cast(u16, h);
}
__device__ __forceinline__ u32 pk2(float a, float b) {
  fp16x2 h = __builtin_amdgcn_cvt_pkrtz(a, b);    // v_cvt_pk_rtz_f16_f32
  return __builtin_bit_cast(u32, h);
}
// async global->LDS DMA, 16B per lane; LDS dest = wave-uniform base + lane*16
__device__ __forceinline__ void dma16(const u16* g, u16* l) {
  __builtin_amdgcn_global_load_lds(
      (const __attribute__((address_space(1))) u32*)g,
      (__attribute__((address_space(3))) u32*)l, 16, 0, 0);
}

// ---------------- single fused fp32 -> f16 convert (x, y, all weights) -----
// Each block converts 1024 contiguous elements of exactly one tensor.
// Ranges (in blocks): x [0,6144), y [6144,12288), Wq-scaled [12288,12864),
// Wkv [12864,14016), Wproj [14016,14592).
// FIXED from round 7: per-range offsets are in ELEMENTS throughout (the
// crash was j = element-index minus BYTE-base -> negative -> OOB).
__global__ __launch_bounds__(256) void cvt_all(
    const float* __restrict__ x, const float* __restrict__ y,
    const float* __restrict__ Wq, const float* __restrict__ Wkv,
    const float* __restrict__ Wp, const float* __restrict__ taup,
    u16* __restrict__ xh, u16* __restrict__ yh,
    u16* __restrict__ wqh, u16* __restrict__ wkh, u16* __restrict__ wph)
{
  const int bx = blockIdx.x;
  const long idx = (long)bx * 1024 + (long)threadIdx.x * 4;  // global elem idx
  const float* in; u16* out; long j; float s = 1.f;
  if (bx < 6144)       { in = x;   out = xh;  j = idx; }
  else if (bx < 12288) { in = y;   out = yh;  j = idx - 6144l * 1024; }
  else if (bx < 12864) {
    float t = *taup;
    float sp = (t > 20.f) ? t : log1pf(expf(t));
    s = (0.125f / (sp + 1e-6f)) * 1.44269504088896340736f;  // qkscale * log2(e)
    in = Wq; out = wqh; j = idx - 12288l * 1024;
  }
  else if (bx < 14016) { in = Wkv; out = wkh; j = idx - 12864l * 1024; }
  else                 { in = Wp;  out = wph; j = idx - 14016l * 1024; }
  float4 f = *(const float4*)(in + j);
  *(uint2*)(out + j) = make_uint2(pk2(f.x * s, f.y * s), pk2(f.z * s, f.w * s));
}

// ---------------- NT GEMM: C[M,N] = A[M,K] @ B[N,K]^T, f16 MFMA, fp32 acc ---
// Round-4 proven structure (gemm<0> ~45 us): tile 128(M) x BN(N), BK=64,
// K=768 (12 iters), 4 waves as 2x2 quadrants, all-DMA staging
// (global_load_lds f16), 2-phase prefetch (issue t+1 before compute t),
// one __syncthreads per iter. Chunk-XOR swizzle on LDS rows.
// MODE 0: FUSED QKV. by<6: A=xh,B=Wq -> q [B,H,N,D] (scale pre-folded);
//         by>=6: A=yh,B=Wkv -> cols[0,768) k; [768,1536) v^T [B,H,D,N]
//         (v^T stored as 8B uint2: 4 consecutive n per lane)
// MODE 2: A=ao,B=Wproj -> fp32 out[M,768] = acc + bias[n]
template<int MODE, int BN, int WPB>
__global__ __launch_bounds__(256, WPB) void gemm_k(
    const u16* __restrict__ A0, const u16* __restrict__ A1,
    const u16* __restrict__ B0, const u16* __restrict__ B1,
    u16* __restrict__ oq, u16* __restrict__ ok, u16* __restrict__ ovt,
    float* __restrict__ outf, const float* __restrict__ bias)
{
  constexpr int NT = BN / 32;                     // n-tiles per wave
  __shared__ __align__(16) u16 As[2][128 * 64];   // [buf][m][k] swizzled, 32 KB
  __shared__ __align__(16) u16 Bs[2][BN * 64];    // [buf][n][k] swizzled
  const int tid = threadIdx.x;
  const int wave = tid >> 6, lane = tid & 63;
  const int quad = lane >> 4, l16 = lane & 15;
  const int wr = wave >> 1, wc = wave & 1;        // wave quadrant (64m x BN/2)
  const int row0 = blockIdx.x * 128;
  const int by = blockIdx.y;

  const u16* A; const u16* Bm; int cb;
  if (MODE == 0) {
    if (by < 6) { A = A0; Bm = B0; cb = by; }
    else        { A = A1; Bm = B1; cb = by - 6; }
  } else {
    A = A0; Bm = B0; cb = by;
  }
  const int col0 = cb * BN;

  const int sub = lane >> 3;                   // row within an 8-row DMA slab
  const int csw = ((lane & 7) ^ sub) * 8;      // swizzled source chunk (elems)

  f32x4 acc[4][NT] = {};

  auto stage = [&](int k0, int bsel) {
    #pragma unroll
    for (int i = 0; i < 4; i++) {
      int ii = wave * 4 + i;                   // A slabs 0..15 (8 rows each)
      dma16(A + (size_t)(row0 + ii * 8 + sub) * 768 + k0 + csw, &As[bsel][ii * 512]);
    }
    #pragma unroll
    for (int i = 0; i < BN / 32; i++) {
      int ii = wave * (BN / 32) + i;           // B slabs
      dma16(Bm + (size_t)(col0 + ii * 8 + sub) * 768 + k0 + csw, &Bs[bsel][ii * 512]);
    }
  };

  stage(0, 0);
  __syncthreads();                             // drain tile-0 DMA

  #pragma unroll 1
  for (int t = 0; t < 12; t++) {
    const int cur = t & 1;
    if (t + 1 < 12) stage((t + 1) << 6, cur ^ 1);   // prefetch next tile
    const u16* Asp = As[cur];
    const u16* Bsp = Bs[cur];
    #pragma unroll
    for (int ks = 0; ks < 2; ks++) {
      half8 af[4], bfr[NT];
      #pragma unroll
      for (int mt = 0; mt < 4; mt++)
        af[mt] = *(const half8*)&Asp[(wr * 64 + mt * 16 + l16) * 64 + (((ks * 4 + quad) ^ (l16 & 7)) * 8)];
      #pragma unroll
      for (int nt = 0; nt < NT; nt++)
        bfr[nt] = *(const half8*)&Bsp[(wc * (BN / 2) + nt * 16 + l16) * 64 + (((ks * 4 + quad) ^ (l16 & 7)) * 8)];
      #pragma unroll
      for (int mt = 0; mt < 4; mt++)
        #pragma unroll
        for (int nt = 0; nt < NT; nt++)
          acc[mt][nt] = __builtin_amdgcn_mfma_f32_16x16x32_f16(af[mt], bfr[nt], acc[mt][nt], 0, 0, 0);
    }
    __syncthreads();   // readers done with buf[cur]; prefetch DMA drained
  }

  // epilogue: C layout col=lane&15, row=quad*4+reg
  #pragma unroll
  for (int mt = 0; mt < 4; mt++)
  #pragma unroll
  for (int nt = 0; nt < NT; nt++) {
    int gm0 = row0 + wr * 64 + mt * 16 + quad * 4;
    int gn = col0 + wc * (BN / 2) + nt * 16 + l16;
    f32x4 v = acc[mt][nt];
    if (MODE == 0) {
      int b = gm0 >> 11, n0 = gm0 & 2047;
      if (by < 6) {
        int h = gn >> 6, d = gn & 63;
        size_t base = (((size_t)(b * NH + h)) * SEQ + n0) * 64 + d;
        #pragma unroll
        for (int r = 0; r < 4; r++) oq[base + (size_t)r * 64] = f2h(v[r]);
      } else if (gn < CDIM) {
        int h = gn >> 6, d = gn & 63;
        size_t base = (((size_t)(b * NH + h)) * SEQ + n0) * 64 + d;
        #pragma unroll
        for (int r = 0; r < 4; r++) ok[base + (size_t)r * 64] = f2h(v[r]);
      } else {
        int c = gn - CDIM;
        int h = c >> 6, d = c & 63;
        *(uint2*)&ovt[(((size_t)(b * NH + h)) * 64 + d) * SEQ + n0] =
            make_uint2(pk2(v[0], v[1]), pk2(v[2], v[3]));   // V^T: 4 consecutive n
      }
    } else {
      float bv = bias[gn];
      #pragma unroll
      for (int r = 0; r < 4; r++)
        outf[(size_t)(gm0 + r) * CDIM + gn] = v[r] + bv;
    }
  }
}

// ---------------- flash attention (transposed-S, f16, no-max softmax) ------
// Round-4 proven kernel (67.7 us). QBLK=128, grid 768, chunked XCD swizzle
// (96 blocks = 6 whole heads per XCD -> 3 MB K/V per 4 MB L2). 4 waves x 32
// q-rows. KV tile 64, 2-phase double-buffered DMA staging, chunk-XOR swizzle.
// St = K Q^T (softmax rows per-lane); fixed-shift softmax p=exp2(s);
// swizzled Ps round-trip for C->A relayout; row-sum l on the matrix pipe
// (MFMA vs ones; lacc rows == oacc rows); s_setprio around MFMA clusters.
__global__ __launch_bounds__(256, 3) void attn_kernel(
    const u16* __restrict__ Q, const u16* __restrict__ Kb,
    const u16* __restrict__ Vtg, u16* __restrict__ Ob)
{
  __shared__ __align__(16) u16 Ks[2][64 * 64];    // [buf][kk][d] swizzled, 2x8 KB
  __shared__ __align__(16) u16 Vs[2][64 * 64];    // [buf][d][kk] swizzled, 2x8 KB
  __shared__ __align__(16) u16 Ps[4 * 16 * 64];   // per-wave 16x64 swizzled, 8 KB

  // bijective chunked XCD swizzle: 768 blocks = 8 XCDs x 96
  const int bid = (blockIdx.x & 7) * 96 + (blockIdx.x >> 3);
  const int qt = bid & 15;
  const int bh = bid >> 4;
  const int b = bh / NH, h = bh % NH;
  const u16* Qp = Q   + (size_t)bh * SEQ * 64;
  const u16* Kp = Kb  + (size_t)bh * SEQ * 64;
  const u16* Vp = Vtg + (size_t)bh * 64 * SEQ;

  const int tid = threadIdx.x;
  const int wave = tid >> 6, lane = tid & 63;
  const int quad = lane >> 4, l16 = lane & 15;
  const int sub = lane >> 3;
  const int csw = ((lane & 7) ^ sub) * 8;
  u16* Pw = Ps + wave * 16 * 64;

  half8 vone;
  #pragma unroll
  for (int j = 0; j < 8; j++) vone[j] = (_Float16)1.0f;

  // Q fragments (B-operand): Q[m=l16][d=ks*32+quad*8+j], scale pre-folded
  half8 qf[2][2];
  #pragma unroll
  for (int mt = 0; mt < 2; mt++)
    #pragma unroll
    for (int ks = 0; ks < 2; ks++)
      qf[mt][ks] = *(const half8*)(Qp + (size_t)(qt * 128 + wave * 32 + mt * 16 + l16) * 64 + ks * 32 + quad * 8);

  f32x4 oacc[2][4] = {};
  f32x4 lacc[2] = {};                          // row-sums via MFMA w/ ones

  auto stage = [&](int kt, int bsel) {
    #pragma unroll
    for (int i = 0; i < 2; i++) {
      int ii = wave * 2 + i;                   // slabs 0..7 (8 rows each)
      dma16(Kp + (size_t)(kt * 64 + ii * 8 + sub) * 64 + csw, &Ks[bsel][ii * 512]);
      dma16(Vp + (size_t)(ii * 8 + sub) * SEQ + kt * 64 + csw, &Vs[bsel][ii * 512]);
    }
  };

  stage(0, 0);
  __syncthreads();                             // drain tile-0 DMA

  #pragma unroll 1
  for (int kt = 0; kt < SEQ / 64; kt++) {
    const int cur = kt & 1;
    if (kt + 1 < SEQ / 64) stage(kt + 1, cur ^ 1);   // prefetch next K/V tile
    const u16* Ksp = Ks[cur];
    const u16* Vsp = Vs[cur];

    // St = K Q^T : sacc[mt][ntk] holds St[kk=ntk*16+quad*4+r][m=l16]
    f32x4 sacc[2][4] = {};
    __builtin_amdgcn_s_setprio(1);
    #pragma unroll
    for (int ks = 0; ks < 2; ks++) {
      #pragma unroll
      for (int ntk = 0; ntk < 4; ntk++) {
        half8 kf = *(const half8*)&Ksp[(ntk * 16 + l16) * 64 + (((ks * 4 + quad) ^ (l16 & 7)) * 8)];
        #pragma unroll
        for (int mt = 0; mt < 2; mt++)
          sacc[mt][ntk] = __builtin_amdgcn_mfma_f32_16x16x32_f16(kf, qf[mt][ks], sacc[mt][ntk], 0, 0, 0);
      }
    }
    __builtin_amdgcn_s_setprio(0);

    // softmax (fixed shift): p = exp2(s); P -> swizzled Ps (C->A layout), per mt
    half8 pf[2][2];
    #pragma unroll
    for (int mt = 0; mt < 2; mt++) {
      #pragma unroll
      for (int ntk = 0; ntk < 4; ntk++) {
        float p0 = __builtin_amdgcn_exp2f(sacc[mt][ntk][0]);
        float p1 = __builtin_amdgcn_exp2f(sacc[mt][ntk][1]);
        float p2 = __builtin_amdgcn_exp2f(sacc[mt][ntk][2]);
        float p3 = __builtin_amdgcn_exp2f(sacc[mt][ntk][3]);
        *(uint2*)&Pw[l16 * 64 + (((ntk * 2 + (quad >> 1)) ^ (l16 & 7)) * 8) + (quad & 1) * 4] =
            make_uint2(pk2(p0, p1), pk2(p2, p3));
      }
      pf[mt][0] = *(const half8*)&Pw[l16 * 64 + ((quad ^ (l16 & 7)) * 8)];
      pf[mt][1] = *(const half8*)&Pw[l16 * 64 + (((4 + quad) ^ (l16 & 7)) * 8)];
    }

    // O += P V (vf reused across mt); l += P 1 on the matrix pipe
    __builtin_amdgcn_s_setprio(1);
    #pragma unroll
    for (int ks = 0; ks < 2; ks++) {
      #pragma unroll
      for (int dt = 0; dt < 4; dt++) {
        half8 vf = *(const half8*)&Vsp[(dt * 16 + l16) * 64 + (((ks * 4 + quad) ^ (l16 & 7)) * 8)];
        #pragma unroll
        for (int mt = 0; mt < 2; mt++)
          oacc[mt][dt] = __builtin_amdgcn_mfma_f32_16x16x32_f16(pf[mt][ks], vf, oacc[mt][dt], 0, 0, 0);
      }
      #pragma unroll
      for (int mt = 0; mt < 2; mt++)
        lacc[mt] = __builtin_amdgcn_mfma_f32_16x16x32_f16(pf[mt][ks], vone, lacc[mt], 0, 0, 0);
    }
    __builtin_amdgcn_s_setprio(0);

    __syncthreads();   // readers done with buf[cur]; prefetch DMA drained
  }

  // epilogue: O / l -> ao[b][n][h*64+d] (f16); lacc row layout == oacc rows
  #pragma unroll
  for (int mt = 0; mt < 2; mt++) {
    #pragma unroll
    for (int r = 0; r < 4; r++) {
      float inv = 1.0f / lacc[mt][r];
      int n = qt * 128 + wave * 32 + mt * 16 + quad * 4 + r;
      size_t base = ((size_t)b * SEQ + n) * CDIM + h * 64;
      #pragma unroll
      for (int dt = 0; dt < 4; dt++)
        Ob[base + dt * 16 + l16] = f2h(oacc[mt][dt][r] * inv);
    }
  }
}

// ---------------- launch ----------------
extern "C" void kernel_launch(void* const* d_in, const int* in_sizes, int n_in,
                              void* d_out, int out_size, void* d_ws, size_t ws_size,
                              hipStream_t stream)
{
  const float* x     = (const float*)d_in[0];
  const float* y     = (const float*)d_in[1];
  const float* Wq    = (const float*)d_in[2];
  const float* Wkv   = (const float*)d_in[3];
  const float* taup  = (const float*)d_in[4];
  const float* Wproj = (const float*)d_in[5];
  const float* bproj = (const float*)d_in[6];
  float* out = (float*)d_out;

  char* ws = (char*)d_ws;
  size_t off = 0;
  auto alloc = [&](size_t bytes) { char* p = ws + off; off += bytes; return p; };
  u16* xh  = (u16*)alloc(8192ull * 768 * 2);
  u16* yh  = (u16*)alloc(8192ull * 768 * 2);
  u16* wqh = (u16*)alloc(768ull * 768 * 2);
  u16* wkh = (u16*)alloc(1536ull * 768 * 2);
  u16* wph = (u16*)alloc(768ull * 768 * 2);
  u16* qb  = (u16*)alloc(8192ull * 768 * 2);   // [B,H,N,D] f16, scale folded
  u16* kb  = (u16*)alloc(8192ull * 768 * 2);   // [B,H,N,D]
  u16* vtb = (u16*)alloc(8192ull * 768 * 2);   // [B,H,D,N]
  u16* ao  = (u16*)alloc(8192ull * 768 * 2);   // [B,N,C]

  // one fused convert kernel: x, y, Wq(scaled), Wkv, Wproj
  cvt_all<<<14592, 256, 0, stream>>>(x, y, Wq, Wkv, Wproj, taup,
                                     xh, yh, wqh, wkh, wph);

  // fused QKV GEMM: by<6 -> Q (N=768), by in [6,18) -> KV (N=1536), BN=128
  gemm_k<0, 128, 2><<<dim3(64, 18), 256, 0, stream>>>(xh, yh, wqh, wkh, qb, kb, vtb, nullptr, nullptr);
  attn_kernel<<<dim3(768), 256, 0, stream>>>(qb, kb, vtb, ao);
  gemm_k<2, 64, 3><<<dim3(64, 12), 256, 0, stream>>>(ao, nullptr, wph, nullptr, nullptr, nullptr, nullptr, out, bproj);
}